// Round 8
// baseline (50.726 us; speedup 1.0000x reference)
//
#include <hip/hip_runtime.h>

#define KDIM 256
#define DWIN 20
#define NOBS 8192
#define TAU  20
#define TROWS (NOBS - TAU)          // 8172
#define KTOT  (DWIN * KDIM)         // 5120
#define KSTEPS (KTOT / 32)          // 160
#define QSTEPS (KSTEPS / 4)         // 40 per K-quarter wave

#define BM 64
#define NBLK_M ((TROWS + BM - 1) / BM)   // 128
#define NBLK   (NBLK_M * 4)              // 512 -> 2 blocks/CU, 4 waves/SIMD

#define AROWS 83                     // 64 + DWIN - 1
#define APAD  264                    // 528B row stride (balanced banks)

// dynamic LDS: A panel 43,824B; C-exchange (<=32KB) reuses it after the loop
#define SRED_OFF  43840
#define DYN_TOTAL 43856

typedef __bf16 bf16x8 __attribute__((ext_vector_type(8)));
typedef float  f32x4  __attribute__((ext_vector_type(4)));
typedef unsigned short u16x8 __attribute__((ext_vector_type(8)));

// ws layout (bytes):
#define WS_BF    0u
#define WS_NEED  (KSTEPS * 16u * 64u * 8u * 2u + 8192u)   // Bf + slack

__device__ __forceinline__ unsigned short f2bf(float f) {
    unsigned int u = __float_as_uint(f);
    unsigned int r = (u + 0x7fffu + ((u >> 16) & 1u)) >> 16;   // RN-even
    return (unsigned short)r;
}

// ---- prep: beta1 -> fragment-major B, coalesced via LDS (proven R7) ----
// Bf[((ks*16 + nt)*64 + lane)*8 + j] = bf16(B[k][n]),
//   k = ks*32 + (lane>>4)*8 + j,  n = nt*16 + (lane&15),  B[k][n] = beta1[n][k&255][k>>8]
__global__ __launch_bounds__(256)
void prep_bfrag_kernel(const float* __restrict__ beta1,
                       unsigned short* __restrict__ Bf,
                       float* __restrict__ out)
{
    __shared__ float L[KTOT];        // 20KB
    const int n   = blockIdx.x;
    const int tid = threadIdx.x;
    if (n == 0 && tid == 0) out[0] = 0.f;   // zero loglik accumulator

    const float4* src = (const float4*)(beta1 + (size_t)n * KTOT);
#pragma unroll
    for (int i = 0; i < 5; ++i)
        ((float4*)L)[tid + i * 256] = src[tid + i * 256];
    __syncthreads();

    const int nt = n >> 4, qn = n & 15;
    for (int c = tid; c < 640; c += 256) {       // c = ks*4 + g
        const int ks = c >> 2, g = c & 3;
        const int kbase = ks * 32 + g * 8;
        u16x8 r;
#pragma unroll
        for (int j = 0; j < 8; ++j) {
            int k = kbase + j;
            r[j] = f2bf(L[(k & 255) * DWIN + (k >> 8)]);
        }
        *(u16x8*)&Bf[(((size_t)ks * 16 + nt) * 64 + g * 16 + qn) * 8] = r;
    }
}

extern __shared__ char dynlds[];

// ---- main GEMM: block 64x64 output, 8 waves = 2 M-halves x 4 K-quarters,
//      barrier-free K-loop, B global->register 2-deep ring, 4 waves/SIMD ----
__global__ __launch_bounds__(512, 4)
void gemm_kernel(const float* __restrict__ obs,
                 const float* __restrict__ beta0,
                 const unsigned short* __restrict__ Bf,
                 float* __restrict__ out)
{
    const int tid  = threadIdx.x;
    const int lane = tid & 63;
    const int w    = tid >> 6;     // 0..7
    const int mh   = w >> 2;       // M-half (32 rows)
    const int kq   = w & 3;        // K-quarter owner
    const int g = lane >> 4;
    const int q = lane & 15;
    const int nb = blockIdx.x & 3;
    const int mb = blockIdx.x >> 2;
    const int i0 = mb * BM;

    unsigned short* ldsA = (unsigned short*)dynlds;

    // B slice: K-step ks at +ks*16KB; nb quadrant +4KB; t-tile +1KB; lane*16B
    const char* bbase = (const char*)Bf + (size_t)(4 * nb) * 1024
                      + (size_t)(QSTEPS * kq) * 16384 + (size_t)lane * 16;

#define BADDR(s) (bbase + (size_t)((s) < QSTEPS ? (s) : QSTEPS - 1) * 16384)
#define LOADB(dst, s)                                                            \
    {                                                                            \
        const char* _p = BADDR(s);                                               \
        _Pragma("unroll")                                                        \
        for (int t = 0; t < 4; ++t)                                              \
            dst[t] = *(const bf16x8*)(_p + t * 1024);                            \
    }

    bf16x8 rbA[4], rbB[4];
    LOADB(rbA, 0)

    // --- stage A panel: rows i0..i0+82 (clamped), fused fp32->bf16 ---
    for (int idx = tid; idx < AROWS * 64; idx += 512) {
        int row = idx >> 6, c4 = idx & 63;
        int grow = min(i0 + row, NOBS - 1);
        float4 v = ((const float4*)obs)[(size_t)grow * 64 + c4];
        ushort4 r;
        r.x = f2bf(v.x); r.y = f2bf(v.y); r.z = f2bf(v.z); r.w = f2bf(v.w);
        *(ushort4*)&ldsA[row * APAD + c4 * 4] = r;
    }
    __syncthreads();

    f32x4 acc[2][4];
#pragma unroll
    for (int m = 0; m < 2; ++m)
#pragma unroll
        for (int t = 0; t < 4; ++t)
            acc[m][t] = (f32x4){0.f, 0.f, 0.f, 0.f};

#define COMPUTE(s, breg)                                                         \
    {                                                                            \
        const int _ks = QSTEPS * kq + (s);                                       \
        const int _acol = ((_ks & 7) * 32 + g * 8);                              \
        const int _aro  = (_ks >> 3);                                            \
        bf16x8 _af[2];                                                           \
        _Pragma("unroll")                                                        \
        for (int m = 0; m < 2; ++m)                                              \
            _af[m] = *(const bf16x8*)&ldsA[(mh * 32 + m * 16 + q + _aro) * APAD + _acol]; \
        _Pragma("unroll")                                                        \
        for (int t = 0; t < 4; ++t)                                              \
            _Pragma("unroll")                                                    \
            for (int m = 0; m < 2; ++m)                                          \
                acc[m][t] = __builtin_amdgcn_mfma_f32_16x16x32_bf16(_af[m], (breg)[t], acc[m][t], 0, 0, 0); \
    }

#pragma unroll 1
    for (int s2 = 0; s2 < QSTEPS; s2 += 2) {
        LOADB(rbB, s2 + 1)
        COMPUTE(s2 + 0, rbA)
        LOADB(rbA, s2 + 2)
        COMPUTE(s2 + 1, rbB)
    }

    // --- K-quarter reduction through LDS (reuses A region; peak 32KB) ---
    __syncthreads();
    f32x4* pc = (f32x4*)dynlds;
    if (kq >= 2) {                                  // round A write: kq 2,3
        f32x4* dst = pc + (size_t)((mh * 2 + (kq - 2)) * 8) * 64 + lane;
#pragma unroll
        for (int m = 0; m < 2; ++m)
#pragma unroll
            for (int t = 0; t < 4; ++t)
                dst[(m * 4 + t) * 64] = acc[m][t];
    }
    __syncthreads();
    if (kq < 2) {                                   // round A add: kq 0,1
        const f32x4* sp = pc + (size_t)((mh * 2 + kq) * 8) * 64 + lane;
#pragma unroll
        for (int m = 0; m < 2; ++m)
#pragma unroll
            for (int t = 0; t < 4; ++t)
                acc[m][t] += sp[(m * 4 + t) * 64];
    }
    __syncthreads();
    if (kq == 1) {                                  // round B write: kq 1
        f32x4* dst = pc + (size_t)(mh * 8) * 64 + lane;
#pragma unroll
        for (int m = 0; m < 2; ++m)
#pragma unroll
            for (int t = 0; t < 4; ++t)
                dst[(m * 4 + t) * 64] = acc[m][t];
    }
    __syncthreads();

    double part = 0.0;
    if (kq == 0) {                                  // final add + epilogue
        const f32x4* sp = pc + (size_t)(mh * 8) * 64 + lane;
#pragma unroll
        for (int m = 0; m < 2; ++m)
#pragma unroll
            for (int t = 0; t < 4; ++t)
                acc[m][t] += sp[(m * 4 + t) * 64];

#pragma unroll
        for (int t = 0; t < 4; ++t) {
            const int col = nb * 64 + t * 16 + q;
            const float b0v = beta0[col];
#pragma unroll
            for (int m = 0; m < 2; ++m) {
#pragma unroll
                for (int r = 0; r < 4; ++r) {
                    const int row = i0 + mh * 32 + m * 16 + 4 * g + r;  // C/D: row=(lane>>4)*4+reg
                    if (row < TROWS) {
                        float lam = acc[m][t][r] + b0v;
                        out[1 + (size_t)row * KDIM + col] = lam;
                        float o = obs[(size_t)(row + TAU) * KDIM + col];
                        part += (double)o * (double)__logf(lam) - (double)lam;
                    }
                }
            }
        }
#pragma unroll
        for (int off = 32; off > 0; off >>= 1) part += __shfl_down(part, off, 64);
    }

    double* sred = (double*)(dynlds + SRED_OFF);
    if (kq == 0 && lane == 0) sred[mh] = part;
    __syncthreads();
    if (tid == 0) atomicAdd(out, (float)(sred[0] + sred[1]));
}

// ================= fallback fp32 path (R1, proven) =================
#define BM_OLD 16
#define NBLK_OLD ((TROWS + BM_OLD - 1) / BM_OLD)   // 511

__global__ __launch_bounds__(KDIM, 2)
void old_lam_kernel(const float* __restrict__ obs,
                    const float* __restrict__ beta0,
                    const float* __restrict__ beta1,
                    float* __restrict__ out,
                    double* __restrict__ partials)
{
    const int k  = threadIdx.x;
    const int i0 = blockIdx.x * BM_OLD;
    const int nr = min(BM_OLD, TROWS - i0);
    const int smax = nr + DWIN - 1;

    float acc[BM_OLD];
#pragma unroll
    for (int r = 0; r < BM_OLD; ++r) acc[r] = 0.f;

    const float* __restrict__ b1k = beta1 + (size_t)k * (KDIM * DWIN);

    for (int b = 0; b < KDIM; ++b) {
        float br[DWIN];
        const float4* qd = (const float4*)(b1k + b * DWIN);
#pragma unroll
        for (int v = 0; v < DWIN / 4; ++v) {
            float4 t = qd[v];
            br[4*v+0] = t.x; br[4*v+1] = t.y; br[4*v+2] = t.z; br[4*v+3] = t.w;
        }
        float wv[BM_OLD + DWIN - 1];
#pragma unroll
        for (int s = 0; s < BM_OLD + DWIN - 1; ++s)
            wv[s] = (s < smax) ? obs[(size_t)(i0 + s) * KDIM + b] : 0.f;
#pragma unroll
        for (int r = 0; r < BM_OLD; ++r)
#pragma unroll
            for (int a = 0; a < DWIN; ++a)
                acc[r] = fmaf(wv[r + a], br[a], acc[r]);
    }

    const float b0 = beta0[k];
    double part = 0.0;
    for (int r = 0; r < nr; ++r) {
        float lam = acc[r] + b0;
        out[1 + (size_t)(i0 + r) * KDIM + k] = lam;
        float o = obs[(size_t)(i0 + r + TAU) * KDIM + k];
        part += (double)(o * logf(lam) - lam);
    }

    __shared__ double sred2[KDIM];
    sred2[k] = part;
    __syncthreads();
    for (int off = KDIM / 2; off > 0; off >>= 1) {
        if (k < off) sred2[k] += sred2[k + off];
        __syncthreads();
    }
    if (k == 0) partials[blockIdx.x] = sred2[0];
}

__global__ void reduce_final_kernel(const double* __restrict__ partials,
                                    float* __restrict__ out, int n)
{
    __shared__ double sr[256];
    double v = 0.0;
    for (int i = threadIdx.x; i < n; i += 256) v += partials[i];
    sr[threadIdx.x] = v;
    __syncthreads();
    for (int off = 128; off > 0; off >>= 1) {
        if (threadIdx.x < off) sr[threadIdx.x] += sr[threadIdx.x + off];
        __syncthreads();
    }
    if (threadIdx.x == 0) out[0] = (float)sr[0];
}
// ===================================================================

extern "C" void kernel_launch(void* const* d_in, const int* in_sizes, int n_in,
                              void* d_out, int out_size, void* d_ws, size_t ws_size,
                              hipStream_t stream)
{
    const float* obs   = (const float*)d_in[0];
    const float* beta0 = (const float*)d_in[1];
    const float* beta1 = (const float*)d_in[2];
    float* out = (float*)d_out;

    if (ws_size >= (size_t)WS_NEED) {
        unsigned short* Bf = (unsigned short*)((char*)d_ws + WS_BF);

        (void)hipFuncSetAttribute(reinterpret_cast<const void*>(gemm_kernel),
                                  hipFuncAttributeMaxDynamicSharedMemorySize,
                                  DYN_TOTAL);

        hipLaunchKernelGGL(prep_bfrag_kernel, dim3(KDIM), dim3(256), 0, stream,
                           beta1, Bf, out);
        hipLaunchKernelGGL(gemm_kernel, dim3(NBLK), dim3(512), DYN_TOTAL, stream,
                           obs, beta0, Bf, out);
    } else {
        double* partials = (double*)d_ws;
        hipLaunchKernelGGL(old_lam_kernel, dim3(NBLK_OLD), dim3(KDIM), 0, stream,
                           obs, beta0, beta1, out, partials);
        hipLaunchKernelGGL(reduce_final_kernel, dim3(1), dim3(256), 0, stream,
                           partials, out, NBLK_OLD);
    }
}

// Round 9
// 42.310 us; speedup vs baseline: 1.1989x; 1.1989x over previous
//
#include <hip/hip_runtime.h>

#define KDIM 256
#define DWIN 20
#define NOBS 8192
#define TAU  20
#define TROWS (NOBS - TAU)          // 8172
#define KTOT  (DWIN * KDIM)         // 5120
#define KSTEPS (KTOT / 32)          // 160
#define QSTEPS (KSTEPS / 4)         // 40 per wave (K-quarter)

#define BM 64
#define NBLK_M ((TROWS + BM - 1) / BM)   // 128
#define NBLK   (NBLK_M * 4)              // 512

#define AROWS 83                     // 64 + DWIN - 1
#define APAD  280                    // 560B row stride (2-way bank alias = free)

// dynamic LDS: A panel (46,480B) overlaps the 64KB partial-C exchange region
#define PC_BYTES  65536
#define SRED_OFF  PC_BYTES
#define DYN_TOTAL (PC_BYTES + 64)

typedef __bf16 bf16x8 __attribute__((ext_vector_type(8)));
typedef float  f32x4  __attribute__((ext_vector_type(4)));
typedef unsigned short u16x8 __attribute__((ext_vector_type(8)));

// ws layout (bytes):
#define WS_BF    0u
#define WS_NEED  (KSTEPS * 16u * 64u * 8u * 2u + 8192u)

__device__ __forceinline__ unsigned short f2bf(float f) {
    unsigned int u = __float_as_uint(f);
    unsigned int r = (u + 0x7fffu + ((u >> 16) & 1u)) >> 16;   // RN-even
    return (unsigned short)r;
}

// ---- prep: beta1 -> fragment-major B, coalesced via LDS (proven R7/R8) ----
// Bf[((ks*16 + nt)*64 + lane)*8 + j] = bf16(B[k][n]),
//   k = ks*32 + (lane>>4)*8 + j,  n = nt*16 + (lane&15),  B[k][n] = beta1[n][k&255][k>>8]
__global__ __launch_bounds__(256)
void prep_bfrag_kernel(const float* __restrict__ beta1,
                       unsigned short* __restrict__ Bf,
                       float* __restrict__ out)
{
    __shared__ float L[KTOT];        // 20KB
    const int n   = blockIdx.x;
    const int tid = threadIdx.x;
    if (n == 0 && tid == 0) out[0] = 0.f;   // zero loglik accumulator

    const float4* src = (const float4*)(beta1 + (size_t)n * KTOT);
#pragma unroll
    for (int i = 0; i < 5; ++i)
        ((float4*)L)[tid + i * 256] = src[tid + i * 256];
    __syncthreads();

    const int nt = n >> 4, qn = n & 15;
    for (int c = tid; c < 640; c += 256) {       // c = ks*4 + g
        const int ks = c >> 2, g = c & 3;
        const int kbase = ks * 32 + g * 8;
        u16x8 r;
#pragma unroll
        for (int j = 0; j < 8; ++j) {
            int k = kbase + j;
            r[j] = f2bf(L[(k & 255) * DWIN + (k >> 8)]);
        }
        *(u16x8*)&Bf[(((size_t)ks * 16 + nt) * 64 + g * 16 + qn) * 8] = r;
    }
}

extern __shared__ char dynlds[];

// ---- main GEMM: EXACT R5 structure (best measured): block 64x64 output,
//      4 waves K-split, barrier-free loop, B global->reg 2-deep ring.
//      Only change vs R5: loglik via one atomicAdd (no partials/reduce). ----
__global__ __launch_bounds__(256, 2)
void gemm_kernel(const float* __restrict__ obs,
                 const float* __restrict__ beta0,
                 const unsigned short* __restrict__ Bf,
                 float* __restrict__ out)
{
    const int tid  = threadIdx.x;
    const int lane = tid & 63;
    const int w    = tid >> 6;     // wave id: owns K-quarter [40w, 40w+40)
    const int g = lane >> 4;
    const int q = lane & 15;
    const int nb = blockIdx.x & 3;
    const int mb = blockIdx.x >> 2;
    const int i0 = mb * BM;

    unsigned short* ldsA = (unsigned short*)dynlds;

    // B slice pointer: phase s lives at bbase + s*16384, t-tile at +t*1024
    const char* bbase = (const char*)Bf + (size_t)(4 * nb) * 1024
                      + (size_t)(40 * w) * 16384 + (size_t)lane * 16;

    // prefetch B(s=0) into registers before A staging (hides under LDS fill)
    bf16x8 bA[4], bB[4];
#pragma unroll
    for (int t = 0; t < 4; ++t)
        bA[t] = *(const bf16x8*)(bbase + t * 1024);

    // --- stage A panel: rows i0..i0+82 (clamped), fused fp32->bf16 ---
    for (int idx = tid; idx < AROWS * 64; idx += 256) {
        int row = idx >> 6, c4 = idx & 63;
        int grow = min(i0 + row, NOBS - 1);
        float4 v = ((const float4*)obs)[(size_t)grow * 64 + c4];
        ushort4 r;
        r.x = f2bf(v.x); r.y = f2bf(v.y); r.z = f2bf(v.z); r.w = f2bf(v.w);
        *(ushort4*)&ldsA[row * APAD + c4 * 4] = r;
    }
    __syncthreads();

    f32x4 acc[4][4];
#pragma unroll
    for (int m = 0; m < 4; ++m)
#pragma unroll
        for (int t = 0; t < 4; ++t)
            acc[m][t] = (f32x4){0.f, 0.f, 0.f, 0.f};

#define COMPUTE(s, breg)                                                         \
    {                                                                            \
        const int _ks = 40 * w + (s);                                            \
        const int _acol = ((_ks & 7) * 32 + g * 8);                              \
        const int _aro  = (_ks >> 3);                                            \
        bf16x8 _af[4];                                                           \
        _Pragma("unroll")                                                        \
        for (int m = 0; m < 4; ++m)                                              \
            _af[m] = *(const bf16x8*)&ldsA[(m * 16 + q + _aro) * APAD + _acol];  \
        _Pragma("unroll")                                                        \
        for (int t = 0; t < 4; ++t)                                              \
            _Pragma("unroll")                                                    \
            for (int m = 0; m < 4; ++m)                                          \
                acc[m][t] = __builtin_amdgcn_mfma_f32_16x16x32_bf16(_af[m], (breg)[t], acc[m][t], 0, 0, 0); \
    }

#pragma unroll 1
    for (int s = 0; s < QSTEPS; s += 2) {
        // prefetch s+1 while computing s
#pragma unroll
        for (int t = 0; t < 4; ++t)
            bB[t] = *(const bf16x8*)(bbase + (size_t)(s + 1) * 16384 + t * 1024);
        COMPUTE(s, bA)
        // prefetch s+2 while computing s+1
        if (s + 2 < QSTEPS) {
#pragma unroll
            for (int t = 0; t < 4; ++t)
                bA[t] = *(const bf16x8*)(bbase + (size_t)(s + 2) * 16384 + t * 1024);
        }
        COMPUTE(s + 1, bB)
    }

    // --- exchange partial C through LDS (reuses A region) ---
    __syncthreads();
    f32x4* pc = (f32x4*)dynlds;        // 4096 x 16B = 64KB
#pragma unroll
    for (int m = 0; m < 4; ++m)
#pragma unroll
        for (int t = 0; t < 4; ++t)
            pc[((w * 16 + m * 4 + t) << 6) + lane] = acc[m][t];
    __syncthreads();

    // wave w reduces band m=w, fused epilogue
    double part = 0.0;
#pragma unroll
    for (int t = 0; t < 4; ++t) {
        f32x4 sum = pc[((w * 4 + t) << 6) + lane];
#pragma unroll
        for (int wp = 1; wp < 4; ++wp)
            sum += pc[((wp * 16 + w * 4 + t) << 6) + lane];
        const int col = nb * 64 + t * 16 + q;
        const float b0v = beta0[col];
#pragma unroll
        for (int r = 0; r < 4; ++r) {
            const int row = i0 + w * 16 + 4 * g + r;   // C/D: row=(lane>>4)*4+reg
            if (row < TROWS) {
                float lam = sum[r] + b0v;
                out[1 + (size_t)row * KDIM + col] = lam;
                float o = obs[(size_t)(row + TAU) * KDIM + col];
                part += (double)o * (double)__logf(lam) - (double)lam;
            }
        }
    }

#pragma unroll
    for (int off = 32; off > 0; off >>= 1) part += __shfl_down(part, off, 64);
    double* sred = (double*)(dynlds + SRED_OFF);
    if (lane == 0) sred[w] = part;
    __syncthreads();
    if (tid == 0)
        atomicAdd(out, (float)(sred[0] + sred[1] + sred[2] + sred[3]));
}

// ================= fallback fp32 path (R1, proven) =================
#define BM_OLD 16
#define NBLK_OLD ((TROWS + BM_OLD - 1) / BM_OLD)   // 511

__global__ __launch_bounds__(KDIM, 2)
void old_lam_kernel(const float* __restrict__ obs,
                    const float* __restrict__ beta0,
                    const float* __restrict__ beta1,
                    float* __restrict__ out,
                    double* __restrict__ partials)
{
    const int k  = threadIdx.x;
    const int i0 = blockIdx.x * BM_OLD;
    const int nr = min(BM_OLD, TROWS - i0);
    const int smax = nr + DWIN - 1;

    float acc[BM_OLD];
#pragma unroll
    for (int r = 0; r < BM_OLD; ++r) acc[r] = 0.f;

    const float* __restrict__ b1k = beta1 + (size_t)k * (KDIM * DWIN);

    for (int b = 0; b < KDIM; ++b) {
        float br[DWIN];
        const float4* qd = (const float4*)(b1k + b * DWIN);
#pragma unroll
        for (int v = 0; v < DWIN / 4; ++v) {
            float4 t = qd[v];
            br[4*v+0] = t.x; br[4*v+1] = t.y; br[4*v+2] = t.z; br[4*v+3] = t.w;
        }
        float wv[BM_OLD + DWIN - 1];
#pragma unroll
        for (int s = 0; s < BM_OLD + DWIN - 1; ++s)
            wv[s] = (s < smax) ? obs[(size_t)(i0 + s) * KDIM + b] : 0.f;
#pragma unroll
        for (int r = 0; r < BM_OLD; ++r)
#pragma unroll
            for (int a = 0; a < DWIN; ++a)
                acc[r] = fmaf(wv[r + a], br[a], acc[r]);
    }

    const float b0 = beta0[k];
    double part = 0.0;
    for (int r = 0; r < nr; ++r) {
        float lam = acc[r] + b0;
        out[1 + (size_t)(i0 + r) * KDIM + k] = lam;
        float o = obs[(size_t)(i0 + r + TAU) * KDIM + k];
        part += (double)(o * logf(lam) - lam);
    }

    __shared__ double sred2[KDIM];
    sred2[k] = part;
    __syncthreads();
    for (int off = KDIM / 2; off > 0; off >>= 1) {
        if (k < off) sred2[k] += sred2[k + off];
        __syncthreads();
    }
    if (k == 0) partials[blockIdx.x] = sred2[0];
}

__global__ void reduce_final_kernel(const double* __restrict__ partials,
                                    float* __restrict__ out, int n)
{
    __shared__ double sr[256];
    double v = 0.0;
    for (int i = threadIdx.x; i < n; i += 256) v += partials[i];
    sr[threadIdx.x] = v;
    __syncthreads();
    for (int off = 128; off > 0; off >>= 1) {
        if (threadIdx.x < off) sr[threadIdx.x] += sr[threadIdx.x + off];
        __syncthreads();
    }
    if (threadIdx.x == 0) out[0] = (float)sr[0];
}
// ===================================================================

extern "C" void kernel_launch(void* const* d_in, const int* in_sizes, int n_in,
                              void* d_out, int out_size, void* d_ws, size_t ws_size,
                              hipStream_t stream)
{
    const float* obs   = (const float*)d_in[0];
    const float* beta0 = (const float*)d_in[1];
    const float* beta1 = (const float*)d_in[2];
    float* out = (float*)d_out;

    if (ws_size >= (size_t)WS_NEED) {
        unsigned short* Bf = (unsigned short*)((char*)d_ws + WS_BF);

        (void)hipFuncSetAttribute(reinterpret_cast<const void*>(gemm_kernel),
                                  hipFuncAttributeMaxDynamicSharedMemorySize,
                                  DYN_TOTAL);

        hipLaunchKernelGGL(prep_bfrag_kernel, dim3(KDIM), dim3(256), 0, stream,
                           beta1, Bf, out);
        hipLaunchKernelGGL(gemm_kernel, dim3(NBLK), dim3(256), DYN_TOTAL, stream,
                           obs, beta0, Bf, out);
    } else {
        double* partials = (double*)d_ws;
        hipLaunchKernelGGL(old_lam_kernel, dim3(NBLK_OLD), dim3(KDIM), 0, stream,
                           obs, beta0, beta1, out, partials);
        hipLaunchKernelGGL(reduce_final_kernel, dim3(1), dim3(256), 0, stream,
                           partials, out, NBLK_OLD);
    }
}

// Round 10
// 35.275 us; speedup vs baseline: 1.4380x; 1.1994x over previous
//
#include <hip/hip_runtime.h>

#define KDIM 256
#define DWIN 20
#define NOBS 8192
#define TAU  20
#define TROWS (NOBS - TAU)          // 8172
#define KTOT  (DWIN * KDIM)         // 5120
#define KS128 (KTOT / 128)          // 40 K-steps of 128
#define QS128 (KS128 / 4)           // 10 per wave (K-quarter)

#define BM 64
#define NBLK_M ((TROWS + BM - 1) / BM)   // 128
#define NBLK   (NBLK_M * 4)              // 512 -> 2 blocks/CU

#define AROWS 83                     // 64 + DWIN - 1
#define APITCH 272                   // 256B data + 16B pad (17*16B -> clean slots)

// dynamic LDS: A fp8 panel (22,576B) overlapped by 64KB C-exchange
#define PC_BYTES  65536
#define SRED_OFF  PC_BYTES
#define DYN_TOTAL (PC_BYTES + 64)

typedef float f32x4 __attribute__((ext_vector_type(4)));
typedef int   i32x4 __attribute__((ext_vector_type(4)));
typedef int   i32x8 __attribute__((ext_vector_type(8)));

// ws layout (bytes): Bf8 fragment-major fp8 B = 5120*256 = 1,310,720
#define WS_BF    0u
#define WS_NEED  (1310720u + 8192u)

__device__ __forceinline__ i32x8 join8(i32x4 a, i32x4 b) {
    i32x8 r;
    r[0]=a[0]; r[1]=a[1]; r[2]=a[2]; r[3]=a[3];
    r[4]=b[0]; r[5]=b[1]; r[6]=b[2]; r[7]=b[3];
    return r;
}

// pack 4 f32 -> 4 e4m3 bytes
__device__ __forceinline__ unsigned int pk4_fp8(float a, float b, float c, float d) {
    int lo = __builtin_amdgcn_cvt_pk_fp8_f32(a, b, 0, false);
    return (unsigned int)__builtin_amdgcn_cvt_pk_fp8_f32(c, d, lo, true);
}

// ---- prep: beta1 -> fragment-major fp8 B ----
// Bf8[((ks*16 + nt)*64 + lane)*32 + j] = e4m3(B[k][n]),
//   k = ks*128 + (lane>>4)*32 + j,  n = nt*16 + (lane&15),
//   B[k][n] = beta1[n][k&255][k>>8].   One block per n, coalesced loads,
//   LDS stride 21 (pad) to break gather bank pile-up.
__global__ __launch_bounds__(256)
void prep_bfrag_kernel(const float* __restrict__ beta1,
                       unsigned char* __restrict__ Bf8,
                       float* __restrict__ out)
{
    __shared__ float L[KDIM * 21];   // 21,504 B, L[b*21 + a]
    const int n   = blockIdx.x;
    const int tid = threadIdx.x;
    if (n == 0 && tid == 0) out[0] = 0.f;   // zero loglik accumulator

    const float* __restrict__ src = beta1 + (size_t)n * KTOT;
    for (int f = tid; f < KTOT; f += 256)
        L[(f / DWIN) * 21 + (f % DWIN)] = src[f];
    __syncthreads();

    const int nt = n >> 4, qn = n & 15;
    for (int c = tid; c < KS128 * 8; c += 256) {    // c = ks*8 + g*2 + half
        const int ks = c >> 3, g = (c >> 1) & 3, half = c & 1;
        const int kb = ks * 128 + g * 32 + half * 16;
        i32x4 w;
#pragma unroll
        for (int u = 0; u < 4; ++u) {
            const int k0 = kb + u * 4;
            w[u] = (int)pk4_fp8(L[((k0+0) & 255) * 21 + ((k0+0) >> 8)],
                                L[((k0+1) & 255) * 21 + ((k0+1) >> 8)],
                                L[((k0+2) & 255) * 21 + ((k0+2) >> 8)],
                                L[((k0+3) & 255) * 21 + ((k0+3) >> 8)]);
        }
        *(i32x4*)&Bf8[(((size_t)ks * 16 + nt) * 64 + g * 16 + qn) * 32 + half * 16] = w;
    }
}

extern __shared__ char dynlds[];

// ---- main GEMM: MX-fp8 K=128 core on the K-split barrier-free skeleton.
//      block 64x64 output, 4 waves each own 10 K128-steps, B 2-deep reg ring. ----
__global__ __launch_bounds__(256, 2)
void gemm_kernel(const float* __restrict__ obs,
                 const float* __restrict__ beta0,
                 const unsigned char* __restrict__ Bf8,
                 float* __restrict__ out)
{
    const int tid  = threadIdx.x;
    const int lane = tid & 63;
    const int kq   = tid >> 6;     // wave id: owns K128-steps [10kq, 10kq+10)
    const int g = lane >> 4;
    const int q = lane & 15;
    const int nb = blockIdx.x & 3;
    const int mb = blockIdx.x >> 2;
    const int i0 = mb * BM;

    char* ldsA8 = dynlds;          // AROWS x APITCH fp8

    // B addressing: byte = ks*32768 + (nb*4+t)*2048 + lane*32
    const char* bbase = (const char*)Bf8 + (size_t)(nb * 4) * 2048 + (size_t)lane * 32;

#define LOADB8(dst, s)                                                           \
    {                                                                            \
        const char* _p = bbase + (size_t)(10 * kq + ((s) < QS128 ? (s) : QS128 - 1)) * 32768; \
        _Pragma("unroll")                                                        \
        for (int t = 0; t < 4; ++t) {                                            \
            i32x4 _lo = *(const i32x4*)(_p + t * 2048);                          \
            i32x4 _hi = *(const i32x4*)(_p + t * 2048 + 16);                     \
            dst[t] = join8(_lo, _hi);                                            \
        }                                                                        \
    }

    i32x8 rbA[4], rbB[4];
    LOADB8(rbA, 0)

    // --- stage A panel as fp8: rows i0..i0+82 (clamped), fused fp32->e4m3 ---
    for (int idx = tid; idx < AROWS * 64; idx += 256) {
        int row = idx >> 6, c4 = idx & 63;
        int grow = min(i0 + row, NOBS - 1);
        float4 v = ((const float4*)obs)[(size_t)grow * 64 + c4];
        *(unsigned int*)(ldsA8 + row * APITCH + c4 * 4) = pk4_fp8(v.x, v.y, v.z, v.w);
    }
    __syncthreads();

    f32x4 acc[4][4];
#pragma unroll
    for (int m = 0; m < 4; ++m)
#pragma unroll
        for (int t = 0; t < 4; ++t)
            acc[m][t] = (f32x4){0.f, 0.f, 0.f, 0.f};

#define COMPUTE8(s, breg)                                                        \
    {                                                                            \
        const int _ks = 10 * kq + (s);                                           \
        const int _aro  = _ks >> 1;                                              \
        const int _acol = (_ks & 1) * 128 + g * 32;                              \
        i32x8 _af[4];                                                            \
        _Pragma("unroll")                                                        \
        for (int m = 0; m < 4; ++m) {                                            \
            const char* _ap = ldsA8 + (m * 16 + q + _aro) * APITCH + _acol;      \
            i32x4 _lo = *(const i32x4*)_ap;                                      \
            i32x4 _hi = *(const i32x4*)(_ap + 16);                               \
            _af[m] = join8(_lo, _hi);                                            \
        }                                                                        \
        _Pragma("unroll")                                                        \
        for (int t = 0; t < 4; ++t)                                              \
            _Pragma("unroll")                                                    \
            for (int m = 0; m < 4; ++m)                                          \
                acc[m][t] = __builtin_amdgcn_mfma_scale_f32_16x16x128_f8f6f4(    \
                    _af[m], (breg)[t], acc[m][t], 0, 0, 0, 0x7f, 0, 0x7f);       \
    }

#pragma unroll 1
    for (int s = 0; s < QS128; s += 2) {
        LOADB8(rbB, s + 1)
        COMPUTE8(s, rbA)
        if (s + 2 < QS128) LOADB8(rbA, s + 2)
        COMPUTE8(s + 1, rbB)
    }

    // --- exchange partial C through LDS (reuses A region) ---
    __syncthreads();
    f32x4* pc = (f32x4*)dynlds;        // 4096 x 16B = 64KB
#pragma unroll
    for (int m = 0; m < 4; ++m)
#pragma unroll
        for (int t = 0; t < 4; ++t)
            pc[((kq * 16 + m * 4 + t) << 6) + lane] = acc[m][t];
    __syncthreads();

    // wave kq reduces band m=kq, fused epilogue
    double part = 0.0;
#pragma unroll
    for (int t = 0; t < 4; ++t) {
        f32x4 sum = pc[((kq * 4 + t) << 6) + lane];
#pragma unroll
        for (int wp = 1; wp < 4; ++wp)
            sum += pc[((wp * 16 + kq * 4 + t) << 6) + lane];
        const int col = nb * 64 + t * 16 + q;
        const float b0v = beta0[col];
#pragma unroll
        for (int r = 0; r < 4; ++r) {
            const int row = i0 + kq * 16 + 4 * g + r;   // C/D: row=(lane>>4)*4+reg
            if (row < TROWS) {
                float lam = sum[r] + b0v;
                out[1 + (size_t)row * KDIM + col] = lam;
                float o = obs[(size_t)(row + TAU) * KDIM + col];
                part += (double)o * (double)__logf(lam) - (double)lam;
            }
        }
    }

#pragma unroll
    for (int off = 32; off > 0; off >>= 1) part += __shfl_down(part, off, 64);
    double* sred = (double*)(dynlds + SRED_OFF);
    if (lane == 0) sred[kq] = part;
    __syncthreads();
    if (tid == 0)
        atomicAdd(out, (float)(sred[0] + sred[1] + sred[2] + sred[3]));
}

// ================= fallback fp32 path (R1, proven) =================
#define BM_OLD 16
#define NBLK_OLD ((TROWS + BM_OLD - 1) / BM_OLD)   // 511

__global__ __launch_bounds__(KDIM, 2)
void old_lam_kernel(const float* __restrict__ obs,
                    const float* __restrict__ beta0,
                    const float* __restrict__ beta1,
                    float* __restrict__ out,
                    double* __restrict__ partials)
{
    const int k  = threadIdx.x;
    const int i0 = blockIdx.x * BM_OLD;
    const int nr = min(BM_OLD, TROWS - i0);
    const int smax = nr + DWIN - 1;

    float acc[BM_OLD];
#pragma unroll
    for (int r = 0; r < BM_OLD; ++r) acc[r] = 0.f;

    const float* __restrict__ b1k = beta1 + (size_t)k * (KDIM * DWIN);

    for (int b = 0; b < KDIM; ++b) {
        float br[DWIN];
        const float4* qd = (const float4*)(b1k + b * DWIN);
#pragma unroll
        for (int v = 0; v < DWIN / 4; ++v) {
            float4 t = qd[v];
            br[4*v+0] = t.x; br[4*v+1] = t.y; br[4*v+2] = t.z; br[4*v+3] = t.w;
        }
        float wv[BM_OLD + DWIN - 1];
#pragma unroll
        for (int s = 0; s < BM_OLD + DWIN - 1; ++s)
            wv[s] = (s < smax) ? obs[(size_t)(i0 + s) * KDIM + b] : 0.f;
#pragma unroll
        for (int r = 0; r < BM_OLD; ++r)
#pragma unroll
            for (int a = 0; a < DWIN; ++a)
                acc[r] = fmaf(wv[r + a], br[a], acc[r]);
    }

    const float b0 = beta0[k];
    double part = 0.0;
    for (int r = 0; r < nr; ++r) {
        float lam = acc[r] + b0;
        out[1 + (size_t)(i0 + r) * KDIM + k] = lam;
        float o = obs[(size_t)(i0 + r + TAU) * KDIM + k];
        part += (double)(o * logf(lam) - lam);
    }

    __shared__ double sred2[KDIM];
    sred2[k] = part;
    __syncthreads();
    for (int off = KDIM / 2; off > 0; off >>= 1) {
        if (k < off) sred2[k] += sred2[k + off];
        __syncthreads();
    }
    if (k == 0) partials[blockIdx.x] = sred2[0];
}

__global__ void reduce_final_kernel(const double* __restrict__ partials,
                                    float* __restrict__ out, int n)
{
    __shared__ double sr[256];
    double v = 0.0;
    for (int i = threadIdx.x; i < n; i += 256) v += partials[i];
    sr[threadIdx.x] = v;
    __syncthreads();
    for (int off = 128; off > 0; off >>= 1) {
        if (threadIdx.x < off) sr[threadIdx.x] += sr[threadIdx.x + off];
        __syncthreads();
    }
    if (threadIdx.x == 0) out[0] = (float)sr[0];
}
// ===================================================================

extern "C" void kernel_launch(void* const* d_in, const int* in_sizes, int n_in,
                              void* d_out, int out_size, void* d_ws, size_t ws_size,
                              hipStream_t stream)
{
    const float* obs   = (const float*)d_in[0];
    const float* beta0 = (const float*)d_in[1];
    const float* beta1 = (const float*)d_in[2];
    float* out = (float*)d_out;

    if (ws_size >= (size_t)WS_NEED) {
        unsigned char* Bf8 = (unsigned char*)d_ws + WS_BF;

        (void)hipFuncSetAttribute(reinterpret_cast<const void*>(gemm_kernel),
                                  hipFuncAttributeMaxDynamicSharedMemorySize,
                                  DYN_TOTAL);

        hipLaunchKernelGGL(prep_bfrag_kernel, dim3(KDIM), dim3(256), 0, stream,
                           beta1, Bf8, out);
        hipLaunchKernelGGL(gemm_kernel, dim3(NBLK), dim3(256), DYN_TOTAL, stream,
                           obs, beta0, Bf8, out);
    } else {
        double* partials = (double*)d_ws;
        hipLaunchKernelGGL(old_lam_kernel, dim3(NBLK_OLD), dim3(KDIM), 0, stream,
                           obs, beta0, beta1, out, partials);
        hipLaunchKernelGGL(reduce_final_kernel, dim3(1), dim3(256), 0, stream,
                           partials, out, NBLK_OLD);
    }
}